// Round 7
// baseline (178.518 us; speedup 1.0000x reference)
//
#include <hip/hip_runtime.h>
#include <math.h>

#define N_NODES 20000
#define N_EDGES 320000
#define NG 64
#define NEG 0.2f
#define NCHUNK ((N_NODES + 255) / 256)   // 79
#define FLAGBIT (1 << 30)

typedef __attribute__((ext_vector_type(8))) short bf16x8;
typedef __attribute__((ext_vector_type(4))) float f32x4;

__device__ __forceinline__ unsigned short f2bf(float f) {
  unsigned int u = __float_as_uint(f);
  return (unsigned short)((u + 0x7fffu + ((u >> 16) & 1u)) >> 16);
}

// ---------------------------------------------------------------------------
// k_front: ONE kernel, block ranges:
//  [0,192)        wbigfrag: bf16 MFMA B-fragments of Wbig[768][64]
//  192            bfold[64] = bf + concat(b_i,b_t) @ Wf (cooperative)
//  [193,1443)     alpha: 16 nodes/block; ws fold computed per block (LDS);
//                 writes xpad + asrc/adst (both sets)
//  [1443,3943)    hist: atomicAdd dst counts into fill_i/fill_t (pre-zeroed)
// ---------------------------------------------------------------------------
__global__ __launch_bounds__(256) void k_front(
    const float* __restrict__ x,
    const float* __restrict__ W_i, const float* __restrict__ as_i, const float* __restrict__ ad_i,
    const float* __restrict__ W_t, const float* __restrict__ as_t, const float* __restrict__ ad_t,
    const float* __restrict__ Wf, const float* __restrict__ bf,
    const float* __restrict__ b_i, const float* __restrict__ b_t,
    const int* __restrict__ ei0, const int* __restrict__ ei1,
    unsigned short* __restrict__ wbigfrag, float* __restrict__ bfold,
    float* __restrict__ xpad,
    float* __restrict__ asrc0, float* __restrict__ adst0,
    float* __restrict__ asrc1, float* __restrict__ adst1,
    int* __restrict__ fill0, int* __restrict__ fill1) {
  __shared__ float bred[4][64];
  __shared__ float wsA[20][64];
  __shared__ float xsA[16][20];
  int b = blockIdx.x, t = threadIdx.x;
  if (b < 192) {
    int idx = b * 256 + t;
    int ct = idx / 12288, rem = idx % 12288;
    int lane = (rem >> 3) & 63, j = rem & 7, ks = rem >> 9;
    int k = ks * 32 + ((lane >> 4) << 3) + j;
    int nc = ct * 16 + (lane & 15);
    float v = 0.f;
    int g = (k >= 384) ? 1 : 0;
    int r = k - g * 384;
    int h = r / 24, c = r - h * 24;
    if (c < 20) {
      const float* W = g ? W_t : W_i;
      const float* wr = W + c * 256 + (h << 4);
      const float* wf = Wf + ((g << 8) + (h << 4)) * 64 + nc;
#pragma unroll
      for (int m = 0; m < 16; ++m) v = fmaf(wr[m], wf[m * 64], v);
    }
    wbigfrag[idx] = f2bf(v);
    return;
  }
  if (b == 192) {
    int wv = t >> 6, j = t & 63;
    float p = 0.f;
    int i0 = wv * 128;
#pragma unroll 4
    for (int i = i0; i < i0 + 128; ++i) {
      float bb = (i < 256) ? b_i[i] : b_t[i - 256];
      p = fmaf(bb, Wf[i * 64 + j], p);
    }
    bred[wv][j] = p;
    __syncthreads();
    if (wv == 0) bfold[j] = bred[0][j] + bred[1][j] + bred[2][j] + bred[3][j] + bf[j];
    return;
  }
  if (b < 1443) {
    int a = b - 193;
    int n0 = a * 16;
    for (int i = t; i < 320; i += 256) {
      int nd = i / 20, k = i % 20;
      xsA[nd][k] = x[(n0 + nd) * 20 + k];
    }
    for (int i = t; i < 1280; i += 256) {
      int k = i >> 6, c = i & 63;
      int set = c >> 5, role = (c >> 4) & 1, h = c & 15;
      const float* W = set ? W_t : W_i;
      const float* av = set ? (role ? ad_t : as_t) : (role ? ad_i : as_i);
      float v = 0.f;
#pragma unroll
      for (int j = 0; j < 16; ++j) v = fmaf(W[k * 256 + h * 16 + j], av[h * 16 + j], v);
      wsA[k][c] = v;
    }
    __syncthreads();
    for (int i = t; i < 512; i += 256) {
      int nd = i >> 5, j = i & 31;
      xpad[(size_t)(n0 + nd) * 32 + j] = (j < 20) ? xsA[nd][j] : 0.f;
    }
#pragma unroll
    for (int i = 0; i < 4; ++i) {
      int wi = i * 256 + t;
      int nd = wi >> 6, c = wi & 63;
      float v = 0.f;
#pragma unroll
      for (int k = 0; k < 20; ++k) v = fmaf(xsA[nd][k], wsA[k][c], v);
      int n = n0 + nd, h = c & 15;
      float* arr = (c >> 5) ? ((c >> 4) & 1 ? adst1 : asrc1)
                            : ((c >> 4) & 1 ? adst0 : asrc0);
      arr[n * 16 + h] = v;
    }
    return;
  }
  // hist
  {
    int hb = b - 1443;
    int set = hb >= 1250;
    int e = (set ? hb - 1250 : hb) * 256 + t;
    const int* ei = set ? ei1 : ei0;
    int* fill = set ? fill1 : fill0;
    atomicAdd(&fill[ei[N_EDGES + e]], 1);
  }
}

// ---------------------------------------------------------------------------
// k_scan: fused decoupled-lookback scan. Grid (79,2). Reads counts from fill,
// publishes chunk aggregate (device-scope atomics), sums predecessor
// aggregates, writes rowptr + fill (=exclusive offsets / scatter cursor).
// All 158 blocks co-resident -> no deadlock.
// ---------------------------------------------------------------------------
__global__ __launch_bounds__(256) void k_scan(
    int* __restrict__ fill0, int* __restrict__ fill1,
    int* __restrict__ rp0, int* __restrict__ rp1,
    int* __restrict__ aggs) {
  int chunk = blockIdx.x, set = blockIdx.y;
  int* fill = set ? fill1 : fill0;
  int* rp = set ? rp1 : rp0;
  int t = threadIdx.x, lane = t & 63, wv = t >> 6;
  int i = chunk * 256 + t;
  int v = (i < N_NODES) ? fill[i] : 0;
  int s = v;
#pragma unroll
  for (int d = 1; d < 64; d <<= 1) {
    int o = __shfl_up(s, d);
    if (lane >= d) s += o;
  }
  __shared__ int wsum[4];
  if (lane == 63) wsum[wv] = s;
  __syncthreads();
  int pre = 0;
#pragma unroll
  for (int j = 0; j < 4; ++j)
    if (j < wv) pre += wsum[j];
  s += pre;
  int agg = wsum[0] + wsum[1] + wsum[2] + wsum[3];
  if (t == 0)
    __hip_atomic_store(&aggs[set * 128 + chunk], agg | FLAGBIT,
                       __ATOMIC_RELEASE, __HIP_MEMORY_SCOPE_AGENT);
  // exclusive prefix over predecessor chunks
  __shared__ int reds[256];
  int part = 0;
  for (int j = t; j < chunk; j += 256) {
    int a;
    do {
      a = __hip_atomic_load(&aggs[set * 128 + j], __ATOMIC_ACQUIRE,
                            __HIP_MEMORY_SCOPE_AGENT);
    } while (!(a & FLAGBIT));
    part += a & (FLAGBIT - 1);
  }
  reds[t] = part;
  __syncthreads();
  for (int st = 128; st > 0; st >>= 1) {
    if (t < st) reds[t] += reds[t + st];
    __syncthreads();
  }
  int carry = reds[0];
  int excl = carry + s - v;
  if (i < N_NODES) {
    rp[i] = excl;
    fill[i] = excl;
    if (i == N_NODES - 1) rp[N_NODES] = excl + v;
  }
}

__global__ void k_scatter(const int* __restrict__ ei0, const int* __restrict__ ei1,
                          int* __restrict__ fill0, int* __restrict__ fill1,
                          unsigned short* __restrict__ srcs0,
                          unsigned short* __restrict__ srcs1) {
  int e = blockIdx.x * blockDim.x + threadIdx.x;
  if (e >= N_EDGES) return;
  const int* ei = blockIdx.y ? ei1 : ei0;
  int* fill = blockIdx.y ? fill1 : fill0;
  unsigned short* srcs = blockIdx.y ? srcs1 : srcs0;
  int d = ei[N_EDGES + e];
  int pos = atomicAdd(&fill[d], 1);
  srcs[pos] = (unsigned short)ei[e];
}

// ---------------------------------------------------------------------------
// k_gat: ONE WAVE PER (node, set), 16-edge batches (= mean degree, so most
// nodes take 1-2 batches). Lane roles per batch: lanes load 16 srcs (4x
// redundant u16), every lane loads one float4-pair of x (row eid=lane&15,
// slot=lane>>4) -> LDS xs[16][36]; attn lane (e4,h16) does 4 exps -> lat.
// Accumulate via same-address-broadcast LDS reads (conflict-free).
// Next batch's srcs prefetched. Writes normalized xagg bf16 [N][768].
// ---------------------------------------------------------------------------
__global__ __launch_bounds__(256) void k_gat(
    const float* __restrict__ xpad,
    const float* __restrict__ asrc0, const float* __restrict__ adst0,
    const float* __restrict__ asrc1, const float* __restrict__ adst1,
    const int* __restrict__ rp0, const unsigned short* __restrict__ srcs0,
    const int* __restrict__ rp1, const unsigned short* __restrict__ srcs1,
    unsigned short* __restrict__ xagg) {
  __shared__ float xsh[4][16][36];
  __shared__ float lath[4][16][16];
  int w4 = threadIdx.x >> 6, lane = threadIdx.x & 63;
  int n = blockIdx.x * 2 + (w4 >> 1);
  int g = w4 & 1;
  int h16 = lane & 15, e4 = lane >> 4;
  int eid = lane & 15, slot = lane >> 4;
  float (*xs)[36] = xsh[w4];
  float (*la)[16] = lath[w4];
  const float* asrc = g ? asrc1 : asrc0;
  const float* adst = g ? adst1 : adst0;
  const int* rp = g ? rp1 : rp0;
  const unsigned short* srcs = g ? srcs1 : srcs0;
  int k0 = rp[n], k1 = rp[n + 1];
  float adn = adst[n * 16 + h16];
  float lacc = 0.f;
  float xa[8];
#pragma unroll
  for (int j = 0; j < 8; ++j) xa[j] = 0.f;
  if (k1 > k0) {
    int sb = (int)srcs[min(k0 + eid, k1 - 1)];
    for (int base = k0; base < k1; base += 16) {
      int sbN = 0;
      if (base + 16 < k1) sbN = (int)srcs[min(base + 16 + eid, k1 - 1)];
      float4 xv0 = *(const float4*)&xpad[(size_t)sb * 32 + slot * 8];
      float4 xv1 = *(const float4*)&xpad[(size_t)sb * 32 + slot * 8 + 4];
      float ex[4];
#pragma unroll
      for (int q = 0; q < 4; ++q) {
        int e = e4 + 4 * q;
        int s = __shfl(sb, e);
        float aa = asrc[s * 16 + h16] + adn;
        aa = aa >= 0.f ? aa : NEG * aa;
        ex[q] = (base + e < k1) ? __expf(aa) : 0.f;
        lacc += ex[q];
        la[e][h16] = ex[q];
      }
      *(float4*)&xs[eid][slot * 8] = xv0;
      *(float4*)&xs[eid][slot * 8 + 4] = xv1;
#pragma unroll
      for (int e = 0; e < 16; ++e) {
        float w = la[e][h16];
        float4 x0 = *(const float4*)&xs[e][e4 * 8];
        float4 x1 = *(const float4*)&xs[e][e4 * 8 + 4];
        xa[0] = fmaf(w, x0.x, xa[0]); xa[1] = fmaf(w, x0.y, xa[1]);
        xa[2] = fmaf(w, x0.z, xa[2]); xa[3] = fmaf(w, x0.w, xa[3]);
        xa[4] = fmaf(w, x1.x, xa[4]); xa[5] = fmaf(w, x1.y, xa[5]);
        xa[6] = fmaf(w, x1.z, xa[6]); xa[7] = fmaf(w, x1.w, xa[7]);
      }
      sb = sbN;
    }
  }
  float lh = lacc + __shfl_xor(lacc, 16);
  lh += __shfl_xor(lh, 32);
  float invl = lh > 0.f ? 1.f / lh : 0.f;
  if (e4 < 3) {
    unsigned int u[4];
#pragma unroll
    for (int q = 0; q < 4; ++q)
      u[q] = (unsigned int)f2bf(xa[2 * q] * invl) |
             ((unsigned int)f2bf(xa[2 * q + 1] * invl) << 16);
    *(uint4*)&xagg[(size_t)n * 768 + g * 384 + h16 * 24 + e4 * 8] = *(uint4*)u;
  }
}

// ---------------------------------------------------------------------------
// k_mlp: 64 nodes/block, layer1 bf16 MFMA ([N,768]@Wbig), layers 2-4 scalar,
// pool atomics; LAST block (atomic counter) computes the graph heads.
// ---------------------------------------------------------------------------
__global__ __launch_bounds__(256) void k_mlp(
    const unsigned short* __restrict__ xagg, const unsigned short* __restrict__ wbigfrag,
    const float* __restrict__ bfold,
    const float* __restrict__ W1m, const float* __restrict__ b1v,
    const float* __restrict__ W2m, const float* __restrict__ b2v,
    const float* __restrict__ W3m, const float* __restrict__ b3v,
    const int* __restrict__ batch,
    float* __restrict__ gsum, int* __restrict__ gcnt, int* __restrict__ donecnt,
    const float* __restrict__ Wce, const float* __restrict__ bce,
    const float* __restrict__ Wcv, const float* __restrict__ bcv,
    float* __restrict__ out) {
  int t = threadIdx.x, w = t >> 6, lane = t & 63;
  int n0 = blockIdx.x * 64;
  __shared__ float o1[64][68];
  __shared__ float o2[64][36];
  __shared__ float o3[64][20];
  __shared__ float o4[64][17];
  __shared__ int bs[64];
  if (t < 64) bs[t] = batch[min(n0 + t, N_NODES - 1)];

  {
    int m = lane & 15, kb = lane >> 4;
    int arow = n0 + w * 16 + m;
    if (arow >= N_NODES) arow = N_NODES - 1;
    const unsigned short* aptr = xagg + (size_t)arow * 768 + kb * 8;
    f32x4 acc0 = {0.f, 0.f, 0.f, 0.f}, acc1 = acc0, acc2 = acc0, acc3 = acc0;
#pragma unroll 4
    for (int ks = 0; ks < 24; ++ks) {
      bf16x8 af = *(const bf16x8*)(aptr + ks * 32);
      const unsigned short* bks = wbigfrag + (size_t)ks * 512 + lane * 8;
      bf16x8 b0 = *(const bf16x8*)(bks);
      bf16x8 b1 = *(const bf16x8*)(bks + 12288);
      bf16x8 b2 = *(const bf16x8*)(bks + 24576);
      bf16x8 b3 = *(const bf16x8*)(bks + 36864);
      acc0 = __builtin_amdgcn_mfma_f32_16x16x32_bf16(af, b0, acc0, 0, 0, 0);
      acc1 = __builtin_amdgcn_mfma_f32_16x16x32_bf16(af, b1, acc1, 0, 0, 0);
      acc2 = __builtin_amdgcn_mfma_f32_16x16x32_bf16(af, b2, acc2, 0, 0, 0);
      acc3 = __builtin_amdgcn_mfma_f32_16x16x32_bf16(af, b3, acc3, 0, 0, 0);
    }
    int col = lane & 15, rg = lane >> 4;
#pragma unroll
    for (int r = 0; r < 4; ++r) {
      int row = w * 16 + rg * 4 + r;
      o1[row][col]      = fmaxf(acc0[r] + bfold[col], 0.f);
      o1[row][16 + col] = fmaxf(acc1[r] + bfold[16 + col], 0.f);
      o1[row][32 + col] = fmaxf(acc2[r] + bfold[32 + col], 0.f);
      o1[row][48 + col] = fmaxf(acc3[r] + bfold[48 + col], 0.f);
    }
  }
  __syncthreads();
  int nd = t >> 2, qo = t & 3;
  {
    float a[8];
#pragma unroll
    for (int j = 0; j < 8; ++j) a[j] = b1v[qo * 8 + j];
#pragma unroll 4
    for (int k = 0; k < 64; ++k) {
      float hv = o1[nd][k];
      const float4 wA = *(const float4*)&W1m[k * 32 + qo * 8];
      const float4 wB = *(const float4*)&W1m[k * 32 + qo * 8 + 4];
      a[0] = fmaf(hv, wA.x, a[0]); a[1] = fmaf(hv, wA.y, a[1]);
      a[2] = fmaf(hv, wA.z, a[2]); a[3] = fmaf(hv, wA.w, a[3]);
      a[4] = fmaf(hv, wB.x, a[4]); a[5] = fmaf(hv, wB.y, a[5]);
      a[6] = fmaf(hv, wB.z, a[6]); a[7] = fmaf(hv, wB.w, a[7]);
    }
#pragma unroll
    for (int j = 0; j < 8; ++j) o2[nd][qo * 8 + j] = fmaxf(a[j], 0.f);
  }
  __syncthreads();
  {
    float a[4];
    const float4 bb = *(const float4*)&b2v[qo * 4];
    a[0] = bb.x; a[1] = bb.y; a[2] = bb.z; a[3] = bb.w;
#pragma unroll 4
    for (int k = 0; k < 32; ++k) {
      float hv = o2[nd][k];
      const float4 ww = *(const float4*)&W2m[k * 16 + qo * 4];
      a[0] = fmaf(hv, ww.x, a[0]); a[1] = fmaf(hv, ww.y, a[1]);
      a[2] = fmaf(hv, ww.z, a[2]); a[3] = fmaf(hv, ww.w, a[3]);
    }
#pragma unroll
    for (int j = 0; j < 4; ++j) o3[nd][qo * 4 + j] = fmaxf(a[j], 0.f);
  }
  __syncthreads();
  {
    float a[4];
    const float4 bb = *(const float4*)&b3v[qo * 4];
    a[0] = bb.x; a[1] = bb.y; a[2] = bb.z; a[3] = bb.w;
#pragma unroll
    for (int k = 0; k < 16; ++k) {
      float hv = o3[nd][k];
      const float4 ww = *(const float4*)&W3m[k * 16 + qo * 4];
      a[0] = fmaf(hv, ww.x, a[0]); a[1] = fmaf(hv, ww.y, a[1]);
      a[2] = fmaf(hv, ww.z, a[2]); a[3] = fmaf(hv, ww.w, a[3]);
    }
#pragma unroll
    for (int j = 0; j < 4; ++j) o4[nd][qo * 4 + j] = fmaxf(a[j], 0.f);
  }
  __syncthreads();
  if (t < 128) {
    int s = t >> 4, js = t & 15;
    int b = bs[0] + s;
    if (b <= bs[63]) {
      float sum = 0.f; int c = 0;
#pragma unroll 8
      for (int ndd = 0; ndd < 64; ++ndd) {
        if (n0 + ndd < N_NODES && bs[ndd] == b) { sum += o4[ndd][js]; ++c; }
      }
      if (c > 0) {
        atomicAdd(&gsum[b * 16 + js], sum);
        if (js == 0) atomicAdd(&gcnt[b], c);
      }
    }
  }
  // ---- last block computes the two heads ----
  __threadfence();
  __shared__ int lastf;
  if (t == 0) {
    int d = __hip_atomic_fetch_add(donecnt, 1, __ATOMIC_ACQ_REL, __HIP_MEMORY_SCOPE_AGENT);
    lastf = (d == (int)gridDim.x - 1);
  }
  __syncthreads();
  if (!lastf) return;
  __shared__ float gs[NG * 16];
  __shared__ float gc[NG];
  for (int i = t; i < NG * 16; i += 256)
    gs[i] = __hip_atomic_load(&gsum[i], __ATOMIC_RELAXED, __HIP_MEMORY_SCOPE_AGENT);
  for (int i = t; i < NG; i += 256)
    gc[i] = (float)__hip_atomic_load(&gcnt[i], __ATOMIC_RELAXED, __HIP_MEMORY_SCOPE_AGENT);
  __syncthreads();
  for (int o = t; o < 384; o += 256) {
    int half = o / 192, idx = o % 192;
    int b = idx / 3, r = idx % 3;
    float inv = gc[b] > 0.f ? 1.f / gc[b] : 1.f;
    const float* Wc = half ? Wcv : Wce;
    const float* bc = half ? bcv : bce;
    float v = bc[r];
#pragma unroll
    for (int j = 0; j < 16; ++j) v = fmaf(gs[b * 16 + j] * inv, Wc[j * 3 + r], v);
    out[o] = v;
  }
}

extern "C" void kernel_launch(void* const* d_in, const int* in_sizes, int n_in,
                              void* d_out, int out_size, void* d_ws, size_t ws_size,
                              hipStream_t stream) {
  const float* x = (const float*)d_in[0];
  const int* ei_i = (const int*)d_in[1];
  const int* ei_t = (const int*)d_in[3];
  const int* batch = (const int*)d_in[5];
  const float* W_i = (const float*)d_in[6];
  const float* as_i = (const float*)d_in[7];
  const float* ad_i = (const float*)d_in[8];
  const float* b_i = (const float*)d_in[9];
  const float* W_t = (const float*)d_in[10];
  const float* as_t = (const float*)d_in[11];
  const float* ad_t = (const float*)d_in[12];
  const float* b_t = (const float*)d_in[13];
  const float* Wf = (const float*)d_in[14];
  const float* bf = (const float*)d_in[15];
  const float* W1 = (const float*)d_in[16];
  const float* b1 = (const float*)d_in[17];
  const float* W2 = (const float*)d_in[18];
  const float* b2 = (const float*)d_in[19];
  const float* W3 = (const float*)d_in[20];
  const float* b3 = (const float*)d_in[21];
  const float* Wce = (const float*)d_in[22];
  const float* bce = (const float*)d_in[23];
  const float* Wcv = (const float*)d_in[24];
  const float* bcv = (const float*)d_in[25];

  char* ws = (char*)d_ws;
  size_t off = 0;
  auto take = [&](size_t bytes) {
    void* p = ws + off;
    off = (off + bytes + 255) & ~(size_t)255;
    return p;
  };
  float* xpad = (float*)take((size_t)N_NODES * 32 * 4);
  unsigned short* xagg = (unsigned short*)take((size_t)N_NODES * 768 * 2);
  unsigned short* wbigfrag = (unsigned short*)take((size_t)49152 * 2);
  float* bfold = (float*)take((size_t)64 * 4);
  float* asrc_i = (float*)take((size_t)N_NODES * 16 * 4);
  float* adst_i = (float*)take((size_t)N_NODES * 16 * 4);
  float* asrc_t = (float*)take((size_t)N_NODES * 16 * 4);
  float* adst_t = (float*)take((size_t)N_NODES * 16 * 4);
  int* rowptr_i = (int*)take((size_t)(N_NODES + 1) * 4);
  int* rowptr_t = (int*)take((size_t)(N_NODES + 1) * 4);
  int* fill_i = (int*)take((size_t)2 * N_NODES * 4);   // fill_i + fill_t contiguous
  int* fill_t = fill_i + N_NODES;
  unsigned short* srcs_i = (unsigned short*)take((size_t)N_EDGES * 2);
  unsigned short* srcs_t = (unsigned short*)take((size_t)N_EDGES * 2);
  // misc contiguous zero region: gsum | gcnt | donecnt | aggs
  float* gsum = (float*)take((size_t)(NG * 16 + NG + 1 + 256) * 4);
  int* gcnt = (int*)(gsum + NG * 16);
  int* donecnt = gcnt + NG;
  int* aggs = donecnt + 1;

  hipMemsetAsync(fill_i, 0, (size_t)2 * N_NODES * 4, stream);
  hipMemsetAsync(gsum, 0, (size_t)(NG * 16 + NG + 1 + 256) * 4, stream);

  k_front<<<3943, 256, 0, stream>>>(x, W_i, as_i, ad_i, W_t, as_t, ad_t,
                                    Wf, bf, b_i, b_t, ei_i, ei_t,
                                    wbigfrag, bfold, xpad,
                                    asrc_i, adst_i, asrc_t, adst_t,
                                    fill_i, fill_t);

  dim3 sgrid(NCHUNK, 2);
  k_scan<<<sgrid, 256, 0, stream>>>(fill_i, fill_t, rowptr_i, rowptr_t, aggs);

  dim3 egrid((N_EDGES + 255) / 256, 2);
  k_scatter<<<egrid, 256, 0, stream>>>(ei_i, ei_t, fill_i, fill_t, srcs_i, srcs_t);

  k_gat<<<N_NODES / 2, 256, 0, stream>>>(xpad, asrc_i, adst_i, asrc_t, adst_t,
                                         rowptr_i, srcs_i, rowptr_t, srcs_t,
                                         xagg);

  k_mlp<<<(N_NODES + 63) / 64, 256, 0, stream>>>(xagg, wbigfrag, bfold,
                                                 W1, b1, W2, b2, W3, b3,
                                                 batch, gsum, gcnt, donecnt,
                                                 Wce, bce, Wcv, bcv, (float*)d_out);
}

// Round 8
// 163.141 us; speedup vs baseline: 1.0943x; 1.0943x over previous
//
#include <hip/hip_runtime.h>
#include <math.h>

#define N_NODES 20000
#define N_EDGES 320000
#define NG 64
#define NEG 0.2f
#define NCHUNK ((N_NODES + 255) / 256)   // 79

typedef __attribute__((ext_vector_type(8))) short bf16x8;
typedef __attribute__((ext_vector_type(4))) float f32x4;

__device__ __forceinline__ unsigned short f2bf(float f) {
  unsigned int u = __float_as_uint(f);
  return (unsigned short)((u + 0x7fffu + ((u >> 16) & 1u)) >> 16);
}

// ---------------------------------------------------------------------------
// k_prep (one kernel, index ranges):
//  [0,1280)        wsall[20][64]: folded alpha weights (set, role, head)
//  [..+49152)      wbigfrag: bf16 MFMA B-fragments of Wbig[768][64]
//  block 197       bfold[64] = bf + concat(b_i,b_t) @ Wf (cooperative)
//  then            zero fill_i / fill_t / gsum / gcnt
// ---------------------------------------------------------------------------
__global__ __launch_bounds__(256) void k_prep(
    const float* __restrict__ W_i, const float* __restrict__ as_i, const float* __restrict__ ad_i,
    const float* __restrict__ W_t, const float* __restrict__ as_t, const float* __restrict__ ad_t,
    const float* __restrict__ Wf, const float* __restrict__ bf,
    const float* __restrict__ b_i, const float* __restrict__ b_t,
    float* __restrict__ wsall, unsigned short* __restrict__ wbigfrag,
    float* __restrict__ bfold,
    int* __restrict__ fill_i, int* __restrict__ fill_t,
    float* __restrict__ gsum, int* __restrict__ gcnt) {
  __shared__ float bred[4][64];
  int idx = blockIdx.x * 256 + threadIdx.x;
  if (idx < 1280) {
    int k = idx >> 6, c = idx & 63;
    int set = c >> 5, role = (c >> 4) & 1, h = c & 15;
    const float* W = set ? W_t : W_i;
    const float* a = set ? (role ? ad_t : as_t) : (role ? ad_i : as_i);
    float v = 0.f;
#pragma unroll
    for (int j = 0; j < 16; ++j) v = fmaf(W[k * 256 + h * 16 + j], a[h * 16 + j], v);
    wsall[idx] = v;
    return;
  }
  idx -= 1280;
  if (idx < 49152) {
    int ct = idx / 12288, rem = idx % 12288;
    int lane = (rem >> 3) & 63, j = rem & 7, ks = rem >> 9;
    int k = ks * 32 + ((lane >> 4) << 3) + j;
    int nc = ct * 16 + (lane & 15);
    float v = 0.f;
    int g = (k >= 384) ? 1 : 0;
    int r = k - g * 384;
    int h = r / 24, c = r - h * 24;
    if (c < 20) {
      const float* W = g ? W_t : W_i;
      const float* wr = W + c * 256 + (h << 4);
      const float* wf = Wf + ((g << 8) + (h << 4)) * 64 + nc;
#pragma unroll
      for (int m = 0; m < 16; ++m) v = fmaf(wr[m], wf[m * 64], v);
    }
    wbigfrag[idx] = f2bf(v);
    return;
  }
  idx -= 49152;
  if (idx < 256) {
    // block 197 exactly: cooperative bfold (4 waves x 128 rows each)
    int t = threadIdx.x, wv = t >> 6, j = t & 63;
    float p = 0.f;
    int i0 = wv * 128;
#pragma unroll 4
    for (int i = i0; i < i0 + 128; ++i) {
      float b = (i < 256) ? b_i[i] : b_t[i - 256];
      p = fmaf(b, Wf[i * 64 + j], p);
    }
    bred[wv][j] = p;
    __syncthreads();
    if (wv == 0) bfold[j] = bred[0][j] + bred[1][j] + bred[2][j] + bred[3][j] + bf[j];
    return;
  }
  idx -= 256;
  if (idx < N_NODES) { fill_i[idx] = 0; return; }
  idx -= N_NODES;
  if (idx < N_NODES) { fill_t[idx] = 0; return; }
  idx -= N_NODES;
  if (idx < NG * 16) { gsum[idx] = 0.f; return; }
  idx -= NG * 16;
  if (idx < NG) gcnt[idx] = 0;
}

// ---------------------------------------------------------------------------
// k_alpha: 16 nodes/block. asrc/adst (both sets) = x @ wsall; writes xpad.
// ---------------------------------------------------------------------------
__global__ __launch_bounds__(256) void k_alpha(
    const float* __restrict__ x, const float* __restrict__ wsall,
    float* __restrict__ xpad,
    float* __restrict__ asrc0, float* __restrict__ adst0,
    float* __restrict__ asrc1, float* __restrict__ adst1) {
  int t = threadIdx.x;
  int n0 = blockIdx.x * 16;
  __shared__ float xs[16][20];
  __shared__ float ws[20][64];
  for (int i = t; i < 16 * 20; i += 256) {
    int nd = i / 20, k = i % 20;
    xs[nd][k] = x[(n0 + nd) * 20 + k];
  }
  for (int i = t; i < 1280; i += 256) ws[i >> 6][i & 63] = wsall[i];
  __syncthreads();
  for (int i = t; i < 512; i += 256) {
    int nd = i >> 5, j = i & 31;
    xpad[(size_t)(n0 + nd) * 32 + j] = (j < 20) ? xs[nd][j] : 0.f;
  }
#pragma unroll
  for (int i = 0; i < 4; ++i) {
    int wi = i * 256 + t;
    int nd = wi >> 6, c = wi & 63;
    float v = 0.f;
#pragma unroll
    for (int k = 0; k < 20; ++k) v = fmaf(xs[nd][k], ws[k][c], v);
    int n = n0 + nd, h = c & 15;
    float* arr = (c >> 5) ? ((c >> 4) & 1 ? adst1 : asrc1)
                          : ((c >> 4) & 1 ? adst0 : asrc0);
    arr[n * 16 + h] = v;
  }
}

// ---------------------------------------------------------------------------
// CSR build
// ---------------------------------------------------------------------------
__global__ void k_hist(const int* __restrict__ ei0, const int* __restrict__ ei1,
                       int* __restrict__ cnt0, int* __restrict__ cnt1) {
  int e = blockIdx.x * blockDim.x + threadIdx.x;
  if (e >= N_EDGES) return;
  if (blockIdx.y == 0)
    atomicAdd(&cnt0[ei0[N_EDGES + e]], 1);
  else
    atomicAdd(&cnt1[ei1[N_EDGES + e]], 1);
}

__global__ __launch_bounds__(256) void k_scan1(
    const int* __restrict__ cnt0, const int* __restrict__ cnt1,
    int* __restrict__ tmp0, int* __restrict__ tmp1, int* __restrict__ csums) {
  int chunk = blockIdx.x, set = blockIdx.y;
  const int* cnt = set ? cnt1 : cnt0;
  int* tmp = set ? tmp1 : tmp0;
  int t = threadIdx.x, lane = t & 63, wv = t >> 6;
  int i = chunk * 256 + t;
  int v = (i < N_NODES) ? cnt[i] : 0;
  int s = v;
#pragma unroll
  for (int d = 1; d < 64; d <<= 1) {
    int o = __shfl_up(s, d);
    if (lane >= d) s += o;
  }
  __shared__ int wsum[4];
  if (lane == 63) wsum[wv] = s;
  __syncthreads();
  int pre = 0;
#pragma unroll
  for (int j = 0; j < 4; ++j)
    if (j < wv) pre += wsum[j];
  s += pre;
  if (i < N_NODES) tmp[i] = s;
  if (t == 255) csums[set * 128 + chunk] = s;
}

__global__ __launch_bounds__(256) void k_scan3(
    const int* __restrict__ tmp0, const int* __restrict__ tmp1,
    const int* __restrict__ csums,
    int* __restrict__ rp0, int* __restrict__ rp1,
    int* __restrict__ fill0, int* __restrict__ fill1) {
  int chunk = blockIdx.x, set = blockIdx.y;
  const int* tmp = set ? tmp1 : tmp0;
  int* rp = set ? rp1 : rp0;
  int* fill = set ? fill1 : fill0;
  __shared__ int soff;
  if (threadIdx.x == 0) {
    int acc = 0;
    for (int cc = 0; cc < chunk; ++cc) acc += csums[set * 128 + cc];
    soff = acc;
  }
  __syncthreads();
  int off = soff;
  int i = chunk * 256 + threadIdx.x;
  if (i >= N_NODES) return;
  int incl = tmp[i];
  int c = fill[i];
  int excl = off + incl - c;
  rp[i] = excl;
  fill[i] = excl;
  if (i == N_NODES - 1) rp[N_NODES] = off + incl;
}

__global__ void k_scatter(const int* __restrict__ ei0, const int* __restrict__ ei1,
                          int* __restrict__ fill0, int* __restrict__ fill1,
                          unsigned short* __restrict__ srcs0,
                          unsigned short* __restrict__ srcs1) {
  int e = blockIdx.x * blockDim.x + threadIdx.x;
  if (e >= N_EDGES) return;
  const int* ei = blockIdx.y ? ei1 : ei0;
  int* fill = blockIdx.y ? fill1 : fill0;
  unsigned short* srcs = blockIdx.y ? srcs1 : srcs0;
  int d = ei[N_EDGES + e];
  int pos = atomicAdd(&fill[d], 1);
  srcs[pos] = (unsigned short)ei[e];
}

// ---------------------------------------------------------------------------
// k_gat: ONE WAVE PER (node, set), 16-edge batches. Lane roles per batch:
// lanes load 16 srcs (u16), every lane loads one float4-pair of x
// (row eid=lane&15, slot=lane>>4) -> LDS xs[16][36]; attn lane (e4,h16)
// does 4 exps -> lat. Accumulate via same-address-broadcast LDS reads.
// Writes normalized xagg bf16 [N][768].
// ---------------------------------------------------------------------------
__global__ __launch_bounds__(256) void k_gat(
    const float* __restrict__ xpad,
    const float* __restrict__ asrc0, const float* __restrict__ adst0,
    const float* __restrict__ asrc1, const float* __restrict__ adst1,
    const int* __restrict__ rp0, const unsigned short* __restrict__ srcs0,
    const int* __restrict__ rp1, const unsigned short* __restrict__ srcs1,
    unsigned short* __restrict__ xagg) {
  __shared__ float xsh[4][16][36];
  __shared__ float lath[4][16][16];
  int w4 = threadIdx.x >> 6, lane = threadIdx.x & 63;
  int n = blockIdx.x * 2 + (w4 >> 1);
  int g = w4 & 1;
  int h16 = lane & 15, e4 = lane >> 4;
  int eid = lane & 15, slot = lane >> 4;
  float (*xs)[36] = xsh[w4];
  float (*la)[16] = lath[w4];
  const float* asrc = g ? asrc1 : asrc0;
  const float* adst = g ? adst1 : adst0;
  const int* rp = g ? rp1 : rp0;
  const unsigned short* srcs = g ? srcs1 : srcs0;
  int k0 = rp[n], k1 = rp[n + 1];
  float adn = adst[n * 16 + h16];
  float lacc = 0.f;
  float xa[8];
#pragma unroll
  for (int j = 0; j < 8; ++j) xa[j] = 0.f;
  if (k1 > k0) {
    int sb = (int)srcs[min(k0 + eid, k1 - 1)];
    for (int base = k0; base < k1; base += 16) {
      int sbN = 0;
      if (base + 16 < k1) sbN = (int)srcs[min(base + 16 + eid, k1 - 1)];
      float4 xv0 = *(const float4*)&xpad[(size_t)sb * 32 + slot * 8];
      float4 xv1 = *(const float4*)&xpad[(size_t)sb * 32 + slot * 8 + 4];
      float ex[4];
#pragma unroll
      for (int q = 0; q < 4; ++q) {
        int e = e4 + 4 * q;
        int s = __shfl(sb, e);
        float aa = asrc[s * 16 + h16] + adn;
        aa = aa >= 0.f ? aa : NEG * aa;
        ex[q] = (base + e < k1) ? __expf(aa) : 0.f;
        lacc += ex[q];
        la[e][h16] = ex[q];
      }
      *(float4*)&xs[eid][slot * 8] = xv0;
      *(float4*)&xs[eid][slot * 8 + 4] = xv1;
#pragma unroll
      for (int e = 0; e < 16; ++e) {
        float w = la[e][h16];
        float4 x0 = *(const float4*)&xs[e][e4 * 8];
        float4 x1 = *(const float4*)&xs[e][e4 * 8 + 4];
        xa[0] = fmaf(w, x0.x, xa[0]); xa[1] = fmaf(w, x0.y, xa[1]);
        xa[2] = fmaf(w, x0.z, xa[2]); xa[3] = fmaf(w, x0.w, xa[3]);
        xa[4] = fmaf(w, x1.x, xa[4]); xa[5] = fmaf(w, x1.y, xa[5]);
        xa[6] = fmaf(w, x1.z, xa[6]); xa[7] = fmaf(w, x1.w, xa[7]);
      }
      sb = sbN;
    }
  }
  float lh = lacc + __shfl_xor(lacc, 16);
  lh += __shfl_xor(lh, 32);
  float invl = lh > 0.f ? 1.f / lh : 0.f;
  if (e4 < 3) {
    unsigned int u[4];
#pragma unroll
    for (int q = 0; q < 4; ++q)
      u[q] = (unsigned int)f2bf(xa[2 * q] * invl) |
             ((unsigned int)f2bf(xa[2 * q + 1] * invl) << 16);
    *(uint4*)&xagg[(size_t)n * 768 + g * 384 + h16 * 24 + e4 * 8] = *(uint4*)u;
  }
}

// ---------------------------------------------------------------------------
// k_mlp: 16 nodes/block (1250 blocks -> ~5 blocks/CU). Wave w computes ONE
// col-tile (16 outputs) of layer 1 via 24-step bf16 MFMA (1 A-load + 1
// B-load per step); layers 2-4 use (node,col) threads; pool over 16 sorted
// nodes with one atomic per (block, graph).
// ---------------------------------------------------------------------------
__global__ __launch_bounds__(256) void k_mlp(
    const unsigned short* __restrict__ xagg, const unsigned short* __restrict__ wbigfrag,
    const float* __restrict__ bfold,
    const float* __restrict__ W1m, const float* __restrict__ b1v,
    const float* __restrict__ W2m, const float* __restrict__ b2v,
    const float* __restrict__ W3m, const float* __restrict__ b3v,
    const int* __restrict__ batch,
    float* __restrict__ gsum, int* __restrict__ gcnt) {
  int t = threadIdx.x, w = t >> 6, lane = t & 63;
  int n0 = blockIdx.x * 16;
  __shared__ float o1[16][68];
  __shared__ float o2[16][36];
  __shared__ float o3[16][20];
  __shared__ float o4[16][17];
  __shared__ int bs[16];
  if (t < 16) bs[t] = batch[n0 + t];

  // ---- layer 1: wave w -> col-tile w ----
  {
    int m = lane & 15, kb = lane >> 4;
    const unsigned short* aptr = xagg + (size_t)(n0 + m) * 768 + kb * 8;
    const unsigned short* bbase = wbigfrag + (size_t)w * 12288 + lane * 8;
    f32x4 acc = {0.f, 0.f, 0.f, 0.f};
#pragma unroll 6
    for (int ks = 0; ks < 24; ++ks) {
      bf16x8 af = *(const bf16x8*)(aptr + ks * 32);
      bf16x8 bfr = *(const bf16x8*)(bbase + (size_t)ks * 512);
      acc = __builtin_amdgcn_mfma_f32_16x16x32_bf16(af, bfr, acc, 0, 0, 0);
    }
    int col = lane & 15, rg = lane >> 4;
#pragma unroll
    for (int r = 0; r < 4; ++r) {
      int row = rg * 4 + r;
      o1[row][w * 16 + col] = fmaxf(acc[r] + bfold[w * 16 + col], 0.f);
    }
  }
  __syncthreads();
  int nd = t >> 4, js = t & 15;
  // ---- layer 2: 64 -> 32 (thread: node nd, cols js and js+16) ----
  {
    float a0 = b1v[js], a1 = b1v[js + 16];
#pragma unroll 8
    for (int k = 0; k < 64; ++k) {
      float hv = o1[nd][k];
      a0 = fmaf(hv, W1m[k * 32 + js], a0);
      a1 = fmaf(hv, W1m[k * 32 + js + 16], a1);
    }
    o2[nd][js] = fmaxf(a0, 0.f);
    o2[nd][js + 16] = fmaxf(a1, 0.f);
  }
  __syncthreads();
  // ---- layer 3: 32 -> 16 ----
  {
    float a = b2v[js];
#pragma unroll
    for (int k = 0; k < 32; ++k) a = fmaf(o2[nd][k], W2m[k * 16 + js], a);
    o3[nd][js] = fmaxf(a, 0.f);
  }
  __syncthreads();
  // ---- layer 4: 16 -> 16 ----
  {
    float a = b3v[js];
#pragma unroll
    for (int k = 0; k < 16; ++k) a = fmaf(o3[nd][k], W3m[k * 16 + js], a);
    o4[nd][js] = fmaxf(a, 0.f);
  }
  __syncthreads();
  // ---- pool over sorted batch: 8 slots x 16 features ----
  if (t < 128) {
    int s = t >> 4, jx = t & 15;
    int b = bs[0] + s;
    if (b <= bs[15]) {
      float sum = 0.f; int c = 0;
#pragma unroll
      for (int ndd = 0; ndd < 16; ++ndd)
        if (bs[ndd] == b) { sum += o4[ndd][jx]; ++c; }
      if (c > 0) {
        atomicAdd(&gsum[b * 16 + jx], sum);
        if (jx == 0) atomicAdd(&gcnt[b], c);
      }
    }
  }
}

__global__ void k_head(const float* __restrict__ gsum, const int* __restrict__ gcnt,
                       const float* __restrict__ Wce, const float* __restrict__ bce,
                       const float* __restrict__ Wcv, const float* __restrict__ bcv,
                       float* __restrict__ out) {
  int t = threadIdx.x;
  if (t >= 384) return;
  int half = t / 192, idx = t % 192;
  int b = idx / 3, r = idx % 3;
  float cnt = (float)gcnt[b];
  float inv = cnt > 0.f ? 1.f / cnt : 1.f;
  const float* Wc = half ? Wcv : Wce;
  const float* bc = half ? bcv : bce;
  float v = bc[r];
#pragma unroll
  for (int j = 0; j < 16; ++j) v = fmaf(gsum[b * 16 + j] * inv, Wc[j * 3 + r], v);
  out[t] = v;
}

extern "C" void kernel_launch(void* const* d_in, const int* in_sizes, int n_in,
                              void* d_out, int out_size, void* d_ws, size_t ws_size,
                              hipStream_t stream) {
  const float* x = (const float*)d_in[0];
  const int* ei_i = (const int*)d_in[1];
  const int* ei_t = (const int*)d_in[3];
  const int* batch = (const int*)d_in[5];
  const float* W_i = (const float*)d_in[6];
  const float* as_i = (const float*)d_in[7];
  const float* ad_i = (const float*)d_in[8];
  const float* b_i = (const float*)d_in[9];
  const float* W_t = (const float*)d_in[10];
  const float* as_t = (const float*)d_in[11];
  const float* ad_t = (const float*)d_in[12];
  const float* b_t = (const float*)d_in[13];
  const float* Wf = (const float*)d_in[14];
  const float* bf = (const float*)d_in[15];
  const float* W1 = (const float*)d_in[16];
  const float* b1 = (const float*)d_in[17];
  const float* W2 = (const float*)d_in[18];
  const float* b2 = (const float*)d_in[19];
  const float* W3 = (const float*)d_in[20];
  const float* b3 = (const float*)d_in[21];
  const float* Wce = (const float*)d_in[22];
  const float* bce = (const float*)d_in[23];
  const float* Wcv = (const float*)d_in[24];
  const float* bcv = (const float*)d_in[25];

  char* ws = (char*)d_ws;
  size_t off = 0;
  auto take = [&](size_t bytes) {
    void* p = ws + off;
    off = (off + bytes + 255) & ~(size_t)255;
    return p;
  };
  float* xpad = (float*)take((size_t)N_NODES * 32 * 4);
  unsigned short* xagg = (unsigned short*)take((size_t)N_NODES * 768 * 2);
  float* wsall = (float*)take((size_t)1280 * 4);
  unsigned short* wbigfrag = (unsigned short*)take((size_t)49152 * 2);
  float* bfold = (float*)take((size_t)64 * 4);
  float* asrc_i = (float*)take((size_t)N_NODES * 16 * 4);
  float* adst_i = (float*)take((size_t)N_NODES * 16 * 4);
  float* asrc_t = (float*)take((size_t)N_NODES * 16 * 4);
  float* adst_t = (float*)take((size_t)N_NODES * 16 * 4);
  int* rowptr_i = (int*)take((size_t)(N_NODES + 1) * 4);
  int* rowptr_t = (int*)take((size_t)(N_NODES + 1) * 4);
  int* fill_i = (int*)take((size_t)N_NODES * 4);
  int* fill_t = (int*)take((size_t)N_NODES * 4);
  int* tmp_i = (int*)take((size_t)N_NODES * 4);
  int* tmp_t = (int*)take((size_t)N_NODES * 4);
  int* csums = (int*)take((size_t)2 * 128 * 4);
  unsigned short* srcs_i = (unsigned short*)take((size_t)N_EDGES * 2);
  unsigned short* srcs_t = (unsigned short*)take((size_t)N_EDGES * 2);
  float* gsum = (float*)take((size_t)NG * 16 * 4);
  int* gcnt = (int*)take((size_t)NG * 4);

  int prep_items = 1280 + 49152 + 256 + N_NODES + N_NODES + NG * 16 + NG;
  k_prep<<<(prep_items + 255) / 256, 256, 0, stream>>>(
      W_i, as_i, ad_i, W_t, as_t, ad_t, Wf, bf, b_i, b_t,
      wsall, wbigfrag, bfold, fill_i, fill_t, gsum, gcnt);

  k_alpha<<<N_NODES / 16, 256, 0, stream>>>(x, wsall, xpad,
                                            asrc_i, adst_i, asrc_t, adst_t);

  dim3 egrid((N_EDGES + 255) / 256, 2);
  k_hist<<<egrid, 256, 0, stream>>>(ei_i, ei_t, fill_i, fill_t);
  dim3 sgrid(NCHUNK, 2);
  k_scan1<<<sgrid, 256, 0, stream>>>(fill_i, fill_t, tmp_i, tmp_t, csums);
  k_scan3<<<sgrid, 256, 0, stream>>>(tmp_i, tmp_t, csums, rowptr_i, rowptr_t,
                                     fill_i, fill_t);
  k_scatter<<<egrid, 256, 0, stream>>>(ei_i, ei_t, fill_i, fill_t, srcs_i, srcs_t);

  k_gat<<<N_NODES / 2, 256, 0, stream>>>(xpad, asrc_i, adst_i, asrc_t, adst_t,
                                         rowptr_i, srcs_i, rowptr_t, srcs_t,
                                         xagg);

  k_mlp<<<N_NODES / 16, 256, 0, stream>>>(xagg, wbigfrag, bfold,
                                          W1, b1, W2, b2, W3, b3,
                                          batch, gsum, gcnt);

  k_head<<<1, 384, 0, stream>>>(gsum, gcnt, Wce, bce, Wcv, bcv, (float*)d_out);
}